// Round 2
// baseline (153.167 us; speedup 1.0000x reference)
//
#include <hip/hip_runtime.h>

typedef short v8s __attribute__((ext_vector_type(8)));
typedef short v4s __attribute__((ext_vector_type(4)));
typedef float v4f __attribute__((ext_vector_type(4)));
typedef float v16f __attribute__((ext_vector_type(16)));

// RNE float -> bf16 (matches float_quantize(exp=8, man=7) for these inputs).
__device__ __forceinline__ unsigned short rne_bf16(float f) {
  unsigned u = __float_as_uint(f);
  return (unsigned short)((u + 0x7fffu + ((u >> 16) & 1u)) >> 16);
}
__device__ __forceinline__ float qbf(float f) {
  return __uint_as_float(((unsigned)rne_bf16(f)) << 16);
}

// ---------------------------------------------------------------------------
// prep_w: w[n][c][kh][kw] fp32 -> Wt[pos][n][c] bf16   (pos = kh*3+kw)
// ---------------------------------------------------------------------------
__global__ __launch_bounds__(128) void prep_w(const float* __restrict__ w,
                                              unsigned short* __restrict__ Wt) {
  int t = blockIdx.x * 128 + threadIdx.x;  // n*64 + c
  if (t >= 8192) return;
  const float* src = w + (size_t)t * 9;
#pragma unroll
  for (int pos = 0; pos < 9; ++pos) Wt[pos * 8192 + t] = rne_bf16(src[pos]);
}

// ---------------------------------------------------------------------------
// conv_fused: implicit GEMM, one output row (b, oh) per WG of 128 threads.
// wave0: ch 0-63, wave1: ch 64-127; wave tile 64ch x 64sp (2 ct x 2 sp MFMAs).
// x quantized+transposed into LDS in-kernel (no Xp round trip).
// W fragments register-double-buffered across the 9 kernel positions.
// ---------------------------------------------------------------------------
#define CS 72  // LDS channel stride (shorts): 144 B, 16B-aligned, no conflicts

__global__ __launch_bounds__(128, 3) void conv_fused(
    const float* __restrict__ x, const unsigned short* __restrict__ Wt,
    const float* __restrict__ bias, float* __restrict__ out) {
  __shared__ __align__(16) unsigned short xs[3 * 58 * CS];  // [row][col][c]

  const int oh = blockIdx.x, b = blockIdx.y;
  const int tid = threadIdx.x;
  const int wv = tid >> 6, lane = tid & 63;
  const int lj = lane & 31, lh = lane >> 5;
  const int ljc = lj < 23 ? lj : 23;  // clamp for sp-tile1 halo reads (dead lanes)

  // ---- W fragment prefetch (starts before staging to hide L2 latency) ----
  const int wBase = wv * 4096 + lj * 64 + lh * 8;
  v8s wA[8], wB[8];
#define PREFETCH(POS, WBUF)                                        \
  {                                                                \
    const unsigned short* wp = Wt + (POS) * 8192 + wBase;          \
    _Pragma("unroll") for (int kk = 0; kk < 4; ++kk) {             \
      WBUF[kk] = *(const v8s*)(wp + kk * 16);                      \
      WBUF[4 + kk] = *(const v8s*)(wp + 2048 + kk * 16);           \
    }                                                              \
  }
  PREFETCH(0, wA);
  PREFETCH(1, wB);

  // ---- stage x: rows oh-1..oh+1, cols -1..56, quantize + transpose ----
  // iteration space 3 rows * 16 chan-quads * 64 cols (58 valid): shift decode,
  // lanes sweep col -> 58-float contiguous global reads per (row,cg,c).
#pragma unroll 4
  for (int i = tid; i < 3072; i += 128) {
    int col = i & 63;
    int cg = (i >> 6) & 15;
    int row = i >> 10;
    if (col < 58) {
      int xh = oh - 1 + row, xw = col - 1;
      v4s pk = (v4s){0, 0, 0, 0};
      if (xh >= 0 && xh < 56 && xw >= 0 && xw < 56) {
        const float* xb = x + ((size_t)(b * 64 + cg * 4)) * 3136 + xh * 56 + xw;
        pk.x = (short)rne_bf16(xb[0]);
        pk.y = (short)rne_bf16(xb[3136]);
        pk.z = (short)rne_bf16(xb[6272]);
        pk.w = (short)rne_bf16(xb[9408]);
      }
      *(v4s*)&xs[(row * 58 + col) * CS + cg * 4] = pk;
    }
  }
  __syncthreads();

  v16f acc[2][2];
#pragma unroll
  for (int a = 0; a < 2; ++a)
#pragma unroll
    for (int s = 0; s < 2; ++s)
#pragma unroll
      for (int e = 0; e < 16; ++e) acc[a][s][e] = 0.0f;

#define COMPUTE(POS, WBUF)                                                     \
  {                                                                            \
    const int kh = (POS) / 3, kw = (POS) % 3;                                  \
    const unsigned short* p0 = xs + (kh * 58 + kw + lj) * CS + lh * 8;         \
    const unsigned short* p1 = xs + (kh * 58 + 32 + kw + ljc) * CS + lh * 8;   \
    _Pragma("unroll") for (int kk = 0; kk < 4; ++kk) {                         \
      v8s pf0 = *(const v8s*)(p0 + kk * 16);                                   \
      v8s pf1 = *(const v8s*)(p1 + kk * 16);                                   \
      acc[0][0] = __builtin_amdgcn_mfma_f32_32x32x16_bf16(WBUF[kk], pf0, acc[0][0], 0, 0, 0); \
      acc[0][1] = __builtin_amdgcn_mfma_f32_32x32x16_bf16(WBUF[kk], pf1, acc[0][1], 0, 0, 0); \
      acc[1][0] = __builtin_amdgcn_mfma_f32_32x32x16_bf16(WBUF[4 + kk], pf0, acc[1][0], 0, 0, 0); \
      acc[1][1] = __builtin_amdgcn_mfma_f32_32x32x16_bf16(WBUF[4 + kk], pf1, acc[1][1], 0, 0, 0); \
    }                                                                          \
  }

  // software-pipelined over pos: compute(p) overlaps prefetch(p+2)
  COMPUTE(0, wA); PREFETCH(2, wA);
  COMPUTE(1, wB); PREFETCH(3, wB);
  COMPUTE(2, wA); PREFETCH(4, wA);
  COMPUTE(3, wB); PREFETCH(5, wB);
  COMPUTE(4, wA); PREFETCH(6, wA);
  COMPUTE(5, wB); PREFETCH(7, wB);
  COMPUTE(6, wA); PREFETCH(8, wA);
  COMPUTE(7, wB);
  COMPUTE(8, wA);

  // ---- epilogue: quantized bias + store (C/D layout verified in R1) ----
  const int chb = wv * 64;
  v4f qb[2][4];
#pragma unroll
  for (int ct = 0; ct < 2; ++ct)
#pragma unroll
    for (int g = 0; g < 4; ++g) {
      v4f t = *(const v4f*)(bias + chb + ct * 32 + g * 8 + lh * 4);
      qb[ct][g].x = qbf(t.x);
      qb[ct][g].y = qbf(t.y);
      qb[ct][g].z = qbf(t.z);
      qb[ct][g].w = qbf(t.w);
    }

  float* ob = out + (size_t)b * 128 * 3136 + oh * 56;
#pragma unroll
  for (int ct = 0; ct < 2; ++ct) {
#pragma unroll
    for (int r = 0; r < 16; ++r) {
      int ch = chb + ct * 32 + (r & 3) + 8 * (r >> 2) + 4 * lh;
      float* pr = ob + (size_t)ch * 3136;
      float bv = (r & 3) == 0   ? qb[ct][r >> 2].x
                 : (r & 3) == 1 ? qb[ct][r >> 2].y
                 : (r & 3) == 2 ? qb[ct][r >> 2].z
                                : qb[ct][r >> 2].w;
      pr[lj] = acc[ct][0][r] + bv;             // ow 0..31
      if (lj < 24) pr[32 + lj] = acc[ct][1][r] + bv;  // ow 32..55
    }
  }
}

extern "C" void kernel_launch(void* const* d_in, const int* in_sizes, int n_in,
                              void* d_out, int out_size, void* d_ws, size_t ws_size,
                              hipStream_t stream) {
  const float* x = (const float*)d_in[0];     // [32,64,56,56]
  const float* w = (const float*)d_in[1];     // [128,64,3,3]
  const float* bias = (const float*)d_in[2];  // [128]
  float* out = (float*)d_out;                 // [32,128,56,56] fp32

  unsigned short* Wt = (unsigned short*)d_ws;  // 9*128*64 bf16 = 147 KB

  prep_w<<<64, 128, 0, stream>>>(w, Wt);
  conv_fused<<<dim3(56, 32), 128, 0, stream>>>(x, Wt, bias, out);
}

// Round 3
// 125.163 us; speedup vs baseline: 1.2237x; 1.2237x over previous
//
#include <hip/hip_runtime.h>

typedef short v8s __attribute__((ext_vector_type(8)));
typedef float v4f __attribute__((ext_vector_type(4)));
typedef float v16f __attribute__((ext_vector_type(16)));

// RNE float -> bf16 (matches float_quantize(exp=8, man=7) for these inputs).
__device__ __forceinline__ unsigned short rne_bf16(float f) {
  unsigned u = __float_as_uint(f);
  return (unsigned short)((u + 0x7fffu + ((u >> 16) & 1u)) >> 16);
}
__device__ __forceinline__ float qbf(float f) {
  return __uint_as_float(((unsigned)rne_bf16(f)) << 16);
}

#define CS 72  // LDS channel stride (shorts): 144 B, keeps 16-B grain everywhere

// ---------------------------------------------------------------------------
// prep: blocks 0..1791 quantize+transpose x[b][c][h][w] -> Xp[b][h+1][w+1][c]
// (padded 58x58 NHWC bf16, borders zeroed); blocks 1792..1823 reorder weights
// w[n][c][kh][kw] -> Wt[pos][n][c] bf16.
// ---------------------------------------------------------------------------
__global__ __launch_bounds__(256) void prep(const float* __restrict__ x,
                                            const float* __restrict__ w,
                                            unsigned short* __restrict__ Xp,
                                            unsigned short* __restrict__ Wt) {
  const int blk = blockIdx.x;
  const int tid = threadIdx.x;

  if (blk >= 1792) {  // ---- weight reorder: t = n*64+c ----
    int t = (blk - 1792) * 256 + tid;  // 0..8191
    const float* src = w + (size_t)t * 9;
#pragma unroll
    for (int pos = 0; pos < 9; ++pos) Wt[pos * 8192 + t] = rne_bf16(src[pos]);
    return;
  }

  const int b = blk / 56, h = blk % 56;
  __shared__ __align__(16) unsigned short tile[56 * CS];  // [w][c]

  // zero pad borders (ws is re-poisoned before every launch)
  unsigned short* rowp = Xp + (((size_t)b * 58 + (h + 1)) * 58) * 64;
  if (tid < 64) { rowp[tid] = 0; rowp[57 * 64 + tid] = 0; }
  if (h == 0) {
    unsigned short* r0 = Xp + ((size_t)b * 58 * 58) * 64;
    unsigned short* r57 = r0 + (size_t)57 * 58 * 64;
    for (int i = tid; i < 58 * 64; i += 256) { r0[i] = 0; r57[i] = 0; }
  }

  // phase 1: 448 slots = 8 chan-octets * 56 w; reads coalesced along w
#pragma unroll
  for (int it = 0; it < 2; ++it) {
    int i = it * 256 + tid;
    if (i < 448) {
      int c8 = i / 56, ww = i - c8 * 56;
      const float* xb = x + ((size_t)(b * 64 + c8 * 8)) * 3136 + h * 56 + ww;
      v8s pk;
#pragma unroll
      for (int j = 0; j < 8; ++j) pk[j] = (short)rne_bf16(xb[(size_t)j * 3136]);
      *(v8s*)&tile[ww * CS + c8 * 8] = pk;
    }
  }
  __syncthreads();

  // phase 2: interior write, 128 B contiguous per w
  unsigned short* dst = Xp + (((size_t)b * 58 + (h + 1)) * 58 + 1) * 64;
#pragma unroll
  for (int it = 0; it < 2; ++it) {
    int i = it * 256 + tid;
    if (i < 448) {
      int ww = i >> 3, cb = i & 7;
      *(v8s*)&dst[ww * 64 + cb * 8] = *(const v8s*)&tile[ww * CS + cb * 8];
    }
  }
}

// ---------------------------------------------------------------------------
// conv: implicit GEMM. Grid (28 row-pairs, 32 b), 512 thr = 8 waves.
// Block tile: 128 ch x 2 oh rows x 56 w. Wave (g,r): 32 ch x 56 sp, one row.
// acc = 2 v16f (32 VGPR); W register-double-buffered across the 9 positions.
// Staging: Xp rows oh0..oh0+3 read LINEARLY (offset i*8) into LDS at 16-B grain.
// ---------------------------------------------------------------------------
__global__ __launch_bounds__(512, 4) void conv(const unsigned short* __restrict__ Xp,
                                               const unsigned short* __restrict__ Wt,
                                               const float* __restrict__ bias,
                                               float* __restrict__ out) {
  __shared__ __align__(16) unsigned short xs[4 * 58 * CS];  // [row][col][c]

  const int oh0 = blockIdx.x * 2, b = blockIdx.y;
  const int tid = threadIdx.x;
  const int wv = tid >> 6, lane = tid & 63;
  const int lj = lane & 31, lh = lane >> 5;
  const int ljc = lj < 23 ? lj : 23;   // clamp halo for sp-tile1 dead lanes
  const int g = wv >> 1, r = wv & 1;   // ch-group (0..3), output row (0..1)

  const int wBase = g * 2048 + lj * 64 + lh * 8;
  v8s wA[4], wB[4];
#define PREFETCH(POS, WBUF)                                   \
  {                                                           \
    const unsigned short* wp = Wt + (POS) * 8192 + wBase;     \
    _Pragma("unroll") for (int kk = 0; kk < 4; ++kk)          \
        WBUF[kk] = *(const v8s*)(wp + kk * 16);               \
  }
  PREFETCH(0, wA);
  PREFETCH(1, wB);

  // stage 4 rows x 58 cols x 64 ch: source is contiguous -> i*8
  const unsigned short* xpb = Xp + (((size_t)b * 58 + oh0) * 58) * 64;
#pragma unroll
  for (int it = 0; it < 4; ++it) {
    int i = it * 512 + tid;
    if (i < 1856) *(v8s*)&xs[(i >> 3) * CS + (i & 7) * 8] = *(const v8s*)&xpb[(size_t)i * 8];
  }
  __syncthreads();

  v16f acc0, acc1;
#pragma unroll
  for (int e = 0; e < 16; ++e) { acc0[e] = 0.0f; acc1[e] = 0.0f; }

#define COMPUTE(POS, WBUF)                                                       \
  {                                                                              \
    const int kh = (POS) / 3, kw = (POS) % 3;                                    \
    const unsigned short* p0 = xs + ((r + kh) * 58 + kw + lj) * CS + lh * 8;     \
    const unsigned short* p1 = xs + ((r + kh) * 58 + 32 + kw + ljc) * CS + lh * 8; \
    _Pragma("unroll") for (int kk = 0; kk < 4; ++kk) {                           \
      v8s pf0 = *(const v8s*)(p0 + kk * 16);                                     \
      v8s pf1 = *(const v8s*)(p1 + kk * 16);                                     \
      acc0 = __builtin_amdgcn_mfma_f32_32x32x16_bf16(WBUF[kk], pf0, acc0, 0, 0, 0); \
      acc1 = __builtin_amdgcn_mfma_f32_32x32x16_bf16(WBUF[kk], pf1, acc1, 0, 0, 0); \
    }                                                                            \
  }

  COMPUTE(0, wA); PREFETCH(2, wA);
  COMPUTE(1, wB); PREFETCH(3, wB);
  COMPUTE(2, wA); PREFETCH(4, wA);
  COMPUTE(3, wB); PREFETCH(5, wB);
  COMPUTE(4, wA); PREFETCH(6, wA);
  COMPUTE(5, wB); PREFETCH(7, wB);
  COMPUTE(6, wA); PREFETCH(8, wA);
  COMPUTE(7, wB);
  COMPUTE(8, wA);

  // epilogue: quantized bias + store (C/D layout verified R1/R2)
  const int chb = g * 32;
  v4f qb[4];
#pragma unroll
  for (int gg = 0; gg < 4; ++gg) {
    v4f t = *(const v4f*)(bias + chb + gg * 8 + lh * 4);
    qb[gg][0] = qbf(t[0]); qb[gg][1] = qbf(t[1]);
    qb[gg][2] = qbf(t[2]); qb[gg][3] = qbf(t[3]);
  }

  float* ob = out + (size_t)b * 128 * 3136 + (oh0 + r) * 56;
#pragma unroll
  for (int e = 0; e < 16; ++e) {
    int ch = chb + (e & 3) + 8 * (e >> 2) + 4 * lh;
    float bv = qb[e >> 2][e & 3];
    float* pr = ob + (size_t)ch * 3136;
    pr[lj] = acc0[e] + bv;                       // ow 0..31
    if (lj < 24) pr[32 + lj] = acc1[e] + bv;     // ow 32..55
  }
}

extern "C" void kernel_launch(void* const* d_in, const int* in_sizes, int n_in,
                              void* d_out, int out_size, void* d_ws, size_t ws_size,
                              hipStream_t stream) {
  const float* x = (const float*)d_in[0];     // [32,64,56,56]
  const float* w = (const float*)d_in[1];     // [128,64,3,3]
  const float* bias = (const float*)d_in[2];  // [128]
  float* out = (float*)d_out;                 // [32,128,56,56] fp32

  unsigned short* Xp = (unsigned short*)d_ws;              // 32*58*58*64 bf16
  const size_t XP_BYTES = (size_t)32 * 58 * 58 * 64 * 2;   // 13,778,944 B
  unsigned short* Wt = (unsigned short*)((char*)d_ws + XP_BYTES);  // 9*128*64

  prep<<<1792 + 32, 256, 0, stream>>>(x, w, Xp, Wt);
  conv<<<dim3(28, 32), 512, 0, stream>>>(Xp, Wt, bias, out);
}

// Round 4
// 124.794 us; speedup vs baseline: 1.2274x; 1.0030x over previous
//
#include <hip/hip_runtime.h>

typedef short v8s __attribute__((ext_vector_type(8)));
typedef float v4f __attribute__((ext_vector_type(4)));
typedef float v16f __attribute__((ext_vector_type(16)));

// RNE float -> bf16 (matches float_quantize(exp=8, man=7) for these inputs).
__device__ __forceinline__ unsigned short rne_bf16(float f) {
  unsigned u = __float_as_uint(f);
  return (unsigned short)((u + 0x7fffu + ((u >> 16) & 1u)) >> 16);
}
__device__ __forceinline__ float qbf(float f) {
  return __uint_as_float(((unsigned)rne_bf16(f)) << 16);
}

#define CS 72  // LDS channel stride (shorts): 144 B = 36 dw, 36%32=4 -> 2-way (free)

// ---------------------------------------------------------------------------
// prep: blocks 0..1791 quantize+transpose x[b][c][h][w] -> Xp[b][h+1][w+1][c]
// (padded 58x58 NHWC bf16, borders zeroed); blocks 1792..1823 reorder weights
// w[n][c][kh][kw] -> Wt[pos][n][c] bf16.
// ---------------------------------------------------------------------------
__global__ __launch_bounds__(256) void prep(const float* __restrict__ x,
                                            const float* __restrict__ w,
                                            unsigned short* __restrict__ Xp,
                                            unsigned short* __restrict__ Wt) {
  const int blk = blockIdx.x;
  const int tid = threadIdx.x;

  if (blk >= 1792) {  // ---- weight reorder: t = n*64+c ----
    int t = (blk - 1792) * 256 + tid;  // 0..8191
    const float* src = w + (size_t)t * 9;
#pragma unroll
    for (int pos = 0; pos < 9; ++pos) Wt[pos * 8192 + t] = rne_bf16(src[pos]);
    return;
  }

  const int b = blk / 56, h = blk % 56;
  __shared__ __align__(16) unsigned short tile[56 * CS];  // [w][c]

  // zero pad borders (ws is re-poisoned before every launch)
  unsigned short* rowp = Xp + (((size_t)b * 58 + (h + 1)) * 58) * 64;
  if (tid < 64) { rowp[tid] = 0; rowp[57 * 64 + tid] = 0; }
  if (h == 0) {
    unsigned short* r0 = Xp + ((size_t)b * 58 * 58) * 64;
    unsigned short* r57 = r0 + (size_t)57 * 58 * 64;
    for (int i = tid; i < 58 * 64; i += 256) { r0[i] = 0; r57[i] = 0; }
  }

  // phase 1: 448 slots = 8 chan-octets * 56 w; reads coalesced along w
#pragma unroll
  for (int it = 0; it < 2; ++it) {
    int i = it * 256 + tid;
    if (i < 448) {
      int c8 = i / 56, ww = i - c8 * 56;
      const float* xb = x + ((size_t)(b * 64 + c8 * 8)) * 3136 + h * 56 + ww;
      v8s pk;
#pragma unroll
      for (int j = 0; j < 8; ++j) pk[j] = (short)rne_bf16(xb[(size_t)j * 3136]);
      *(v8s*)&tile[ww * CS + c8 * 8] = pk;
    }
  }
  __syncthreads();

  // phase 2: interior write, 128 B contiguous per w
  unsigned short* dst = Xp + (((size_t)b * 58 + (h + 1)) * 58 + 1) * 64;
#pragma unroll
  for (int it = 0; it < 2; ++it) {
    int i = it * 256 + tid;
    if (i < 448) {
      int ww = i >> 3, cb = i & 7;
      *(v8s*)&dst[ww * 64 + cb * 8] = *(const v8s*)&tile[ww * CS + cb * 8];
    }
  }
}

// ---------------------------------------------------------------------------
// conv: implicit GEMM. Grid (56 oh, 32 b) = 1792 blocks, 256 thr = 4 waves.
// Block tile: 128 ch x 1 oh row x 56 w. Wave g: 32 ch x 56 sp.
// LDS: 3 staged Xp rows = 25 KB -> 6 blocks/CU -> 24 waves/CU steady state.
// acc = 2 v16f; W register-double-buffered across the 9 positions.
// Staging reads Xp LINEARLY (offset i*8) at 16-B grain.
// ---------------------------------------------------------------------------
__global__ __launch_bounds__(256, 6) void conv(const unsigned short* __restrict__ Xp,
                                               const unsigned short* __restrict__ Wt,
                                               const float* __restrict__ bias,
                                               float* __restrict__ out) {
  __shared__ __align__(16) unsigned short xs[3 * 58 * CS];  // [row][col][c]

  const int oh = blockIdx.x, b = blockIdx.y;
  const int tid = threadIdx.x;
  const int g = tid >> 6, lane = tid & 63;  // g = ch-group 0..3
  const int lj = lane & 31, lh = lane >> 5;
  const int ljc = lj < 23 ? lj : 23;  // clamp halo for sp-tile1 dead lanes

  const int wBase = g * 2048 + lj * 64 + lh * 8;
  v8s wA[4], wB[4];
#define PREFETCH(POS, WBUF)                                   \
  {                                                           \
    const unsigned short* wp = Wt + (POS) * 8192 + wBase;     \
    _Pragma("unroll") for (int kk = 0; kk < 4; ++kk)          \
        WBUF[kk] = *(const v8s*)(wp + kk * 16);               \
  }
  PREFETCH(0, wA);
  PREFETCH(1, wB);

  // stage 3 padded rows (oh..oh+2) x 58 cols x 64 ch: source contiguous
  const unsigned short* xpb = Xp + (((size_t)b * 58 + oh) * 58) * 64;
#pragma unroll
  for (int it = 0; it < 6; ++it) {
    int i = it * 256 + tid;
    if (i < 1392) {
      int rc = i >> 3, cb = i & 7;
      *(v8s*)&xs[rc * CS + cb * 8] = *(const v8s*)&xpb[(size_t)i * 8];
    }
  }
  __syncthreads();

  v16f acc0, acc1;
#pragma unroll
  for (int e = 0; e < 16; ++e) { acc0[e] = 0.0f; acc1[e] = 0.0f; }

#define COMPUTE(POS, WBUF)                                                       \
  {                                                                              \
    const int kh = (POS) / 3, kw = (POS) % 3;                                    \
    const unsigned short* p0 = xs + (kh * 58 + kw + lj) * CS + lh * 8;           \
    const unsigned short* p1 = xs + (kh * 58 + 32 + kw + ljc) * CS + lh * 8;     \
    _Pragma("unroll") for (int kk = 0; kk < 4; ++kk) {                           \
      v8s pf0 = *(const v8s*)(p0 + kk * 16);                                     \
      v8s pf1 = *(const v8s*)(p1 + kk * 16);                                     \
      acc0 = __builtin_amdgcn_mfma_f32_32x32x16_bf16(WBUF[kk], pf0, acc0, 0, 0, 0); \
      acc1 = __builtin_amdgcn_mfma_f32_32x32x16_bf16(WBUF[kk], pf1, acc1, 0, 0, 0); \
    }                                                                            \
  }

  COMPUTE(0, wA); PREFETCH(2, wA);
  COMPUTE(1, wB); PREFETCH(3, wB);
  COMPUTE(2, wA); PREFETCH(4, wA);
  COMPUTE(3, wB); PREFETCH(5, wB);
  COMPUTE(4, wA); PREFETCH(6, wA);
  COMPUTE(5, wB); PREFETCH(7, wB);
  COMPUTE(6, wA); PREFETCH(8, wA);
  COMPUTE(7, wB);
  COMPUTE(8, wA);

  // epilogue: quantized bias + store (C/D layout verified R1-R3)
  const int chb = g * 32;
  v4f qb[4];
#pragma unroll
  for (int gg = 0; gg < 4; ++gg) {
    v4f t = *(const v4f*)(bias + chb + gg * 8 + lh * 4);
    qb[gg][0] = qbf(t[0]); qb[gg][1] = qbf(t[1]);
    qb[gg][2] = qbf(t[2]); qb[gg][3] = qbf(t[3]);
  }

  float* ob = out + (size_t)b * 128 * 3136 + oh * 56;
#pragma unroll
  for (int e = 0; e < 16; ++e) {
    int ch = chb + (e & 3) + 8 * (e >> 2) + 4 * lh;
    float bv = qb[e >> 2][e & 3];
    float* pr = ob + (size_t)ch * 3136;
    pr[lj] = acc0[e] + bv;                    // ow 0..31
    if (lj < 24) pr[32 + lj] = acc1[e] + bv;  // ow 32..55
  }
}

extern "C" void kernel_launch(void* const* d_in, const int* in_sizes, int n_in,
                              void* d_out, int out_size, void* d_ws, size_t ws_size,
                              hipStream_t stream) {
  const float* x = (const float*)d_in[0];     // [32,64,56,56]
  const float* w = (const float*)d_in[1];     // [128,64,3,3]
  const float* bias = (const float*)d_in[2];  // [128]
  float* out = (float*)d_out;                 // [32,128,56,56] fp32

  unsigned short* Xp = (unsigned short*)d_ws;              // 32*58*58*64 bf16
  const size_t XP_BYTES = (size_t)32 * 58 * 58 * 64 * 2;   // 13,778,944 B
  unsigned short* Wt = (unsigned short*)((char*)d_ws + XP_BYTES);  // 9*128*64

  prep<<<1792 + 32, 256, 0, stream>>>(x, w, Xp, Wt);
  conv<<<dim3(56, 32), 256, 0, stream>>>(Xp, Wt, bias, out);
}